// Round 6
// baseline (657.373 us; speedup 1.0000x reference)
//
#include <hip/hip_runtime.h>

#define NROWS 8192
#define DDIM  1024           // elements per row (fp8: also bytes per row)
#define BM 128
#define BN 128
#define BKB 128              // K-bytes per tile iteration
#define MARGIN_F 0.05f
#define FP8_SCALE 8.0f       // power of 2; sims are scaled by 64 in mining space

typedef __attribute__((ext_vector_type(8)))  int   int8v;
typedef __attribute__((ext_vector_type(4)))  int   int4v;
typedef __attribute__((ext_vector_type(16))) float floatx16;

__device__ __forceinline__ void g2lds16(const void* g, void* l) {
  __builtin_amdgcn_global_load_lds(
      (const __attribute__((address_space(1))) void*)g,
      (__attribute__((address_space(3))) void*)l, 16, 0, 0);
}

// prep: 2048 blocks x 256 threads; wave w handles row 4*blockIdx + w.
// Exact fp32 pos_sim, fp32 -> fp8(e4m3, x8) quantize, zero keys + out.
__global__ void prep_kernel(const float* __restrict__ x, const float* __restrict__ y,
                            unsigned int* __restrict__ xq, unsigned int* __restrict__ yq,
                            float* __restrict__ pos, unsigned int* __restrict__ keys,
                            float* __restrict__ out) {
  const int t = threadIdx.x;
  const int lane = t & 63, wave = t >> 6;
  const int row = blockIdx.x * 4 + wave;
  const float4* xr = (const float4*)(x + (size_t)row * DDIM);
  const float4* yr = (const float4*)(y + (size_t)row * DDIM);
  unsigned int* xqr = xq + (size_t)row * 256;
  unsigned int* yqr = yq + (size_t)row * 256;
  float s = 0.f;
#pragma unroll
  for (int u = 0; u < 4; ++u) {
    const float4 a = xr[u * 64 + lane];
    const float4 b = yr[u * 64 + lane];
    s += a.x * b.x + a.y * b.y + a.z * b.z + a.w * b.w;
    int pa = __builtin_amdgcn_cvt_pk_fp8_f32(a.x * FP8_SCALE, a.y * FP8_SCALE, 0, false);
    pa     = __builtin_amdgcn_cvt_pk_fp8_f32(a.z * FP8_SCALE, a.w * FP8_SCALE, pa, true);
    int pb = __builtin_amdgcn_cvt_pk_fp8_f32(b.x * FP8_SCALE, b.y * FP8_SCALE, 0, false);
    pb     = __builtin_amdgcn_cvt_pk_fp8_f32(b.z * FP8_SCALE, b.w * FP8_SCALE, pb, true);
    xqr[u * 64 + lane] = (unsigned int)pa;
    yqr[u * 64 + lane] = (unsigned int)pb;
  }
  for (int m = 32; m; m >>= 1) s += __shfl_down(s, m, 64);
  if (lane == 0) { pos[row] = s; keys[row] = 0u; }
  if (blockIdx.x == 0 && t == 0) out[0] = 0.f;
}

// R14: fair test of the 3-blocks/CU regime (m97/m148 ladder) with FETCH fixed.
// Post-mortems: R12 was purely HBM-bound (dur == hbm_bytes/BW; 294MB FETCH
// from 8x A-restage + bad grid), R13 spilled acc (batched b128 reads pushed
// live regs past the 256/wave cap -> 227MB scratch WRITE). The only structure
// that never spilled/raced is the 2-barrier __syncthreads loop; the only
// untested documented lever is 3 blocks/CU on the 84-VGPR (64x64 wave tile)
// config. So: one 128x128 output tile per block, grid 4096, bounds(256,3)
// (LDS 33KB x3 = 99KB, 84 regs < 170 cap), inner loop = R12 verbatim.
// FETCH control: XCD-aware mapping. xcd = bid&7 owns row-panels
// [xcd*8, xcd*8+8); within an XCD, consecutive blocks walk 8 panels of one
// col-tile then advance col (col-major in time) -> B-tile (128KB) is reused
// 8x while hot in that XCD's L2; A panels (1MB/XCD) stay resident.
// Ideal mine FETCH ~ B 64MB + A 8MB. Tripwire: FETCH>150MB = mapping dead.
__global__ __launch_bounds__(256, 3) void mine_kernel(
    const unsigned char* __restrict__ xq, const unsigned char* __restrict__ yq,
    const float* __restrict__ pos, unsigned int* __restrict__ keys) {
  __shared__ unsigned char As[BM * BKB];  // 16 KB, XOR-swizzled
  __shared__ unsigned char Bs[BN * BKB];  // 16 KB, XOR-swizzled
  __shared__ float pos_s[BM];

  const int t = threadIdx.x;
  // XCD-aware decode: 4096 = 8 xcd * 8 prow * 64 col; local>>3 = col makes
  // each XCD's dispatch order col-major over its 8 row-panels.
  const int bid   = blockIdx.x;
  const int xcd   = bid & 7;
  const int local = bid >> 3;
  const int col   = local >> 3;          // 0..63
  const int prow  = local & 7;           // 0..7
  const int rowBase = (xcd * 8 + prow) * BM;
  const int colBase = col * BN;

  if (t < BM) pos_s[t] = pos[rowBase + t] * (FP8_SCALE * FP8_SCALE);

  const int lane = t & 63;
  const int wave = t >> 6;
  const int wr = wave >> 1, wc = wave & 1;   // 2x2 waves, wave tile 64x64
  const int r31 = lane & 31, kh = lane >> 5;

  const int fragOff = ((2 * kh) ^ (r31 & 7)) << 4;
  const int offA0 = (64 * wr + r31) * BKB + fragOff;   // + mi*32*BKB
  const int offB0 = (64 * wc + r31) * BKB + fragOff;   // + ni*32*BKB

  // Staging (R7/R12-proven): slot c = i*256 + t; row r = i*32 + (t>>3);
  // chunk sw = (t&7)^((t>>3)&7) (i-independent). One VGPR offset; the i and
  // k0 terms are wave-uniform.
  const int stageOff = (t >> 3) * DDIM + (((t & 7) ^ ((t >> 3) & 7)) << 4);
  const int ldsDst   = (wave * 64) * 16;   // + lane*16 added by HW
  const unsigned char* aPan = xq + (size_t)rowBase * DDIM;
  const unsigned char* bPan = yq + (size_t)colBase * DDIM;

  unsigned int key[2][16];
#pragma unroll
  for (int mi = 0; mi < 2; ++mi)
#pragma unroll
    for (int reg = 0; reg < 16; ++reg) key[mi][reg] = 0u;

  floatx16 acc[2][2];
#pragma unroll
  for (int mi = 0; mi < 2; ++mi)
#pragma unroll
    for (int ni = 0; ni < 2; ++ni)
#pragma unroll
      for (int r = 0; r < 16; ++r) acc[mi][ni][r] = 0.f;

  for (int k0 = 0; k0 < DDIM; k0 += BKB) {
    __syncthreads();  // previous iteration's ds_reads done before overwrite
#pragma unroll
    for (int i = 0; i < 4; ++i)
      g2lds16(aPan + (i * 32 * DDIM + k0) + stageOff, &As[(i * 256) * 16 + ldsDst]);
#pragma unroll
    for (int i = 0; i < 4; ++i)
      g2lds16(bPan + (i * 32 * DDIM + k0) + stageOff, &Bs[(i * 256) * 16 + ldsDst]);
    __syncthreads();

#pragma unroll
    for (int ks = 0; ks < 2; ++ks) {
      const int kx = ks << 6;  // ^64 selects the second K-64 of the tile
      int8v af[2];
#pragma unroll
      for (int mi = 0; mi < 2; ++mi) {
        const int oA = (offA0 + mi * 32 * BKB) ^ kx;
        int4v lo = *(const int4v*)&As[oA];
        int4v hi = *(const int4v*)&As[oA ^ 16];
        af[mi] = __builtin_shufflevector(lo, hi, 0, 1, 2, 3, 4, 5, 6, 7);
      }
#pragma unroll
      for (int ni = 0; ni < 2; ++ni) {
        const int oB = (offB0 + ni * 32 * BKB) ^ kx;
        int4v blo = *(const int4v*)&Bs[oB];
        int4v bhi = *(const int4v*)&Bs[oB ^ 16];
        int8v bf = __builtin_shufflevector(blo, bhi, 0, 1, 2, 3, 4, 5, 6, 7);
        acc[0][ni] = __builtin_amdgcn_mfma_scale_f32_32x32x64_f8f6f4(
            af[0], bf, acc[0][ni], 0, 0, 0, 0x7F7F7F7F, 0, 0x7F7F7F7F);
        acc[1][ni] = __builtin_amdgcn_mfma_scale_f32_32x32x64_f8f6f4(
            af[1], bf, acc[1][ni], 0, 0, 0, 0x7F7F7F7F, 0, 0x7F7F7F7F);
      }
    }
  }

  // Key fold (pure VALU). 32x32 C/D layout (HW-verified): col = lane&31,
  // row = (reg&3) + 8*(reg>>2) + 4*(lane>>5).
#pragma unroll
  for (int mi = 0; mi < 2; ++mi) {
#pragma unroll
    for (int reg = 0; reg < 16; ++reg) {
      const int row_l = 64 * wr + 32 * mi + (reg & 3) + 8 * (reg >> 2) + 4 * kh;
      const int row_g = rowBase + row_l;
      const float p = pos_s[row_l];
      unsigned int kk = key[mi][reg];
#pragma unroll
      for (int ni = 0; ni < 2; ++ni) {
        const int c = colBase + 64 * wc + 32 * ni + r31;
        const float v = acc[mi][ni][reg];
        const bool dead = (c == row_g) || (v > p);
        unsigned int u = __float_as_uint(v);
        u ^= (unsigned int)(((int)u) >> 31) | 0x80000000u;
        unsigned int kc = (u & 0xFFFFE000u) | (unsigned int)(8191 - c);
        kc = dead ? 0u : kc;
        kk = kk > kc ? kk : kc;
      }
      key[mi][reg] = kk;
    }
  }

  // One butterfly + one atomic per owned row.
#pragma unroll
  for (int mi = 0; mi < 2; ++mi) {
#pragma unroll
    for (int reg = 0; reg < 16; ++reg) {
      unsigned int kk = key[mi][reg];
#pragma unroll
      for (int m = 1; m <= 16; m <<= 1) {
        unsigned int o = __shfl_xor(kk, m, 64);
        kk = kk > o ? kk : o;
      }
      if (r31 == 0) {
        const int row_l = 64 * wr + 32 * mi + (reg & 3) + 8 * (reg >> 2) + 4 * kh;
        atomicMax(&keys[rowBase + row_l], kk);
      }
    }
  }
}

// Exact fp32 recompute of neg_sim for the mined index + loss reduction.
// 1024 blocks -> ample wave parallelism for the latency-bound gather.
__global__ void final_kernel(const float* __restrict__ x, const float* __restrict__ y,
                             const float* __restrict__ pos,
                             const unsigned int* __restrict__ keys,
                             float* __restrict__ out) {
  const int t = threadIdx.x;
  const int lane = t & 63, wave = t >> 6;
  float accl = 0.f;
#pragma unroll
  for (int i = 0; i < 2; ++i) {
    const int row = blockIdx.x * 8 + i * 4 + wave;
    const unsigned int k = keys[row];
    const int j = (k == 0u) ? 0 : (8191 - (int)(k & 8191u));  // all-masked -> argmax 0
    const float4* xr = (const float4*)(x + (size_t)row * DDIM);
    const float4* yr = (const float4*)(y + (size_t)j * DDIM);
    float s = 0.f;
#pragma unroll
    for (int u = 0; u < 4; ++u) {
      const float4 a = xr[lane + 64 * u];
      const float4 b = yr[lane + 64 * u];
      s += a.x * b.x + a.y * b.y + a.z * b.z + a.w * b.w;
    }
    for (int m = 32; m; m >>= 1) s += __shfl_down(s, m, 64);
    if (lane == 0) {
      const float l = MARGIN_F - pos[row] + s;
      accl += l > 0.f ? l : 0.f;
    }
  }
  __shared__ float ps[4];
  if (lane == 0) ps[wave] = accl;
  __syncthreads();
  if (t == 0) atomicAdd(out, (ps[0] + ps[1] + ps[2] + ps[3]) * (1.0f / (float)NROWS));
}

extern "C" void kernel_launch(void* const* d_in, const int* in_sizes, int n_in,
                              void* d_out, int out_size, void* d_ws, size_t ws_size,
                              hipStream_t stream) {
  const float* x = (const float*)d_in[0];
  const float* y = (const float*)d_in[1];
  float* out = (float*)d_out;

  // ws layout: keys 32 KB | pos 32 KB | xq 8 MB | yq 8 MB
  unsigned int* keys = (unsigned int*)d_ws;
  float* pos = (float*)((char*)d_ws + (size_t)NROWS * 4);
  unsigned char* xq = (unsigned char*)d_ws + (size_t)NROWS * 8;
  unsigned char* yq = xq + (size_t)NROWS * DDIM;

  prep_kernel<<<NROWS / 4, 256, 0, stream>>>(x, y, (unsigned int*)xq, (unsigned int*)yq,
                                             pos, keys, out);
  mine_kernel<<<(NROWS / BM) * (NROWS / BN), 256, 0, stream>>>(xq, yq, pos, keys);
  final_kernel<<<NROWS / 8, 256, 0, stream>>>(x, y, pos, keys, out);
}

// Round 7
// 241.752 us; speedup vs baseline: 2.7192x; 2.7192x over previous
//
#include <hip/hip_runtime.h>

#define NROWS 8192
#define DDIM  1024           // elements per row (fp8: also bytes per row)
#define BM 128
#define BN 256
#define BKB 128              // K-bytes per tile iteration
#define NSTRIPES 8
#define CT_PER_STRIPE 4      // 8192 / (256*8)
#define MARGIN_F 0.05f
#define FP8_SCALE 8.0f       // power of 2; sims are scaled by 64 in mining space

typedef __attribute__((ext_vector_type(8)))  int   int8v;
typedef __attribute__((ext_vector_type(4)))  int   int4v;
typedef __attribute__((ext_vector_type(16))) float floatx16;

__device__ __forceinline__ void g2lds16(const void* g, void* l) {
  __builtin_amdgcn_global_load_lds(
      (const __attribute__((address_space(1))) void*)g,
      (__attribute__((address_space(3))) void*)l, 16, 0, 0);
}

// prep: 2048 blocks x 256 threads; wave w handles row 4*blockIdx + w.
// Exact fp32 pos_sim, fp32 -> fp8(e4m3, x8) quantize, zero keys + out.
__global__ void prep_kernel(const float* __restrict__ x, const float* __restrict__ y,
                            unsigned int* __restrict__ xq, unsigned int* __restrict__ yq,
                            float* __restrict__ pos, unsigned int* __restrict__ keys,
                            float* __restrict__ out) {
  const int t = threadIdx.x;
  const int lane = t & 63, wave = t >> 6;
  const int row = blockIdx.x * 4 + wave;
  const float4* xr = (const float4*)(x + (size_t)row * DDIM);
  const float4* yr = (const float4*)(y + (size_t)row * DDIM);
  unsigned int* xqr = xq + (size_t)row * 256;
  unsigned int* yqr = yq + (size_t)row * 256;
  float s = 0.f;
#pragma unroll
  for (int u = 0; u < 4; ++u) {
    const float4 a = xr[u * 64 + lane];
    const float4 b = yr[u * 64 + lane];
    s += a.x * b.x + a.y * b.y + a.z * b.z + a.w * b.w;
    int pa = __builtin_amdgcn_cvt_pk_fp8_f32(a.x * FP8_SCALE, a.y * FP8_SCALE, 0, false);
    pa     = __builtin_amdgcn_cvt_pk_fp8_f32(a.z * FP8_SCALE, a.w * FP8_SCALE, pa, true);
    int pb = __builtin_amdgcn_cvt_pk_fp8_f32(b.x * FP8_SCALE, b.y * FP8_SCALE, 0, false);
    pb     = __builtin_amdgcn_cvt_pk_fp8_f32(b.z * FP8_SCALE, b.w * FP8_SCALE, pb, true);
    xqr[u * 64 + lane] = (unsigned int)pa;
    yqr[u * 64 + lane] = (unsigned int)pb;
  }
  for (int m = 32; m; m >>= 1) s += __shfl_down(s, m, 64);
  if (lane == 0) { pos[row] = s; keys[row] = 0u; }
  if (blockIdx.x == 0 && t == 0) out[0] = 0.f;
}

// R15 = R8 (proven 123us best) with ONE register-neutral delta: A-fragments
// loaded DIRECTLY global->VGPR (two dwordx4 of 32 contiguous bytes of row
// rowBase+64wr+32mi+r31), bypassing LDS entirely.
// Why sound: (a) A needs no swizzle from global (the LDS swizzle was bank
// bookkeeping only); (b) A is L2-resident by construction -- with all 512
// blocks co-resident, XCD=bid&7=rowblock&7 keeps exactly 8 panels = 1 MB of
// A per XCD L2 (verified arithmetic, matches R8's 101MB FETCH floor);
// (c) af liveness identical to R8's proven no-spill pattern (16 regs
// transient), B staging/reads/epilogue verbatim.
// What it buys: LDS reads 12->8 per wave-ks (port time 51->~34us/CU),
// staging 48->32 KB/step (shorter stage phase, 4 fewer vmem issues/thread),
// LDS 49.6->33 KB. Checkable: SQ_LDS_BANK_CONFLICT must drop to ~4.2M
// (B-only: 1.05M b128 x 4-cyc structural tax). Tripwires: FETCH>150MB =
// A-L2 assumption dead; WRITE>100MB = spill.
__global__ __launch_bounds__(256, 2) void mine_kernel(
    const unsigned char* __restrict__ xq, const unsigned char* __restrict__ yq,
    const float* __restrict__ pos, unsigned int* __restrict__ keys) {
  __shared__ unsigned char Bs[BN * BKB];  // 32 KB, XOR-swizzled
  __shared__ float pos_s[BM];

  const int t = threadIdx.x;
  const int rowBase = blockIdx.x * BM;
  const int stripe  = blockIdx.y;
  if (t < BM) pos_s[t] = pos[rowBase + t] * (FP8_SCALE * FP8_SCALE);

  const int lane = t & 63;
  const int wave = t >> 6;
  const int wr = wave >> 1, wc = wave & 1;   // wave tile 64 rows x 128 cols
  const int r31 = lane & 31, kh = lane >> 5;

  // B ds_read side (R7/R8-proven): chunk c of LDS row r at c^(r&7); lane
  // reads chunk pair (2kh, 2kh+1); ks toggles byte bit6.
  const int fragOff = ((2 * kh) ^ (r31 & 7)) << 4;
  const int offB0 = (128 * wc + r31) * BKB + fragOff;  // ni adds 32*BKB

  // A direct-from-global: lane (r31,kh) owns bytes [kh*32, +32) of each K-64
  // slab of rows rowBase + 64*wr + 32*mi + r31.
  const unsigned char* aRow = xq + (size_t)(rowBase + 64 * wr + r31) * DDIM + kh * 32;

  unsigned int key[2][16];
#pragma unroll
  for (int mi = 0; mi < 2; ++mi)
#pragma unroll
    for (int reg = 0; reg < 16; ++reg) key[mi][reg] = 0u;

  for (int ct = 0; ct < CT_PER_STRIPE; ++ct) {
    const int colBase = stripe * (BN * CT_PER_STRIPE) + ct * BN;

    floatx16 acc[2][4];
#pragma unroll
    for (int mi = 0; mi < 2; ++mi)
#pragma unroll
      for (int ni = 0; ni < 4; ++ni)
#pragma unroll
        for (int r = 0; r < 16; ++r) acc[mi][ni][r] = 0.f;

    for (int k0 = 0; k0 < DDIM; k0 += BKB) {
      __syncthreads();  // previous iteration's B ds_reads done before overwrite
      // Stage B only (32 KB, 8 issues/thread) via global_load_lds width=16.
      // 8 consecutive lanes fill one row's 128-B segment -> coalesced;
      // swizzle carried by the global source address.
#pragma unroll
      for (int i = 0; i < 8; ++i) {
        const int c  = i * 256 + t;
        const int r  = c >> 3;               // 0..255
        const int sw = (c & 7) ^ (r & 7);
        g2lds16(yq + (size_t)(colBase + r) * DDIM + k0 + sw * 16,
                &Bs[(size_t)(i * 256 + wave * 64) * 16]);
      }
      __syncthreads();

#pragma unroll
      for (int ks = 0; ks < 2; ++ks) {
        const int kx = ks << 6;  // second K-64 of the tile
        int8v af[2];
#pragma unroll
        for (int mi = 0; mi < 2; ++mi) {
          const unsigned char* ap = aRow + (size_t)mi * (32 * DDIM) + k0 + kx;
          int4v lo = *(const int4v*)ap;
          int4v hi = *(const int4v*)(ap + 16);
          af[mi] = __builtin_shufflevector(lo, hi, 0, 1, 2, 3, 4, 5, 6, 7);
        }
#pragma unroll
        for (int ni = 0; ni < 4; ++ni) {
          const int oB = (offB0 + ni * 32 * BKB) ^ kx;
          int4v blo = *(const int4v*)&Bs[oB];
          int4v bhi = *(const int4v*)&Bs[oB ^ 16];
          int8v bf = __builtin_shufflevector(blo, bhi, 0, 1, 2, 3, 4, 5, 6, 7);
          acc[0][ni] = __builtin_amdgcn_mfma_scale_f32_32x32x64_f8f6f4(
              af[0], bf, acc[0][ni], 0, 0, 0, 0x7F7F7F7F, 0, 0x7F7F7F7F);
          acc[1][ni] = __builtin_amdgcn_mfma_scale_f32_32x32x64_f8f6f4(
              af[1], bf, acc[1][ni], 0, 0, 0, 0x7F7F7F7F, 0, 0x7F7F7F7F);
        }
      }
    }

    // Per-ct key update (pure VALU; no shuffles, no atomics).
    // 32x32 C/D layout (HW-verified): col = lane&31,
    // row = (reg&3) + 8*(reg>>2) + 4*(lane>>5).
    int colv[4];
#pragma unroll
    for (int ni = 0; ni < 4; ++ni) colv[ni] = colBase + 128 * wc + 32 * ni + r31;
#pragma unroll
    for (int mi = 0; mi < 2; ++mi) {
#pragma unroll
      for (int reg = 0; reg < 16; ++reg) {
        const int row_l = 64 * wr + 32 * mi + (reg & 3) + 8 * (reg >> 2) + 4 * kh;
        const int row_g = rowBase + row_l;
        const float p = pos_s[row_l];
        unsigned int kk = key[mi][reg];
#pragma unroll
        for (int ni = 0; ni < 4; ++ni) {
          const float v = acc[mi][ni][reg];
          const bool dead = (colv[ni] == row_g) || (v > p);
          unsigned int u = __float_as_uint(v);
          u ^= (unsigned int)(((int)u) >> 31) | 0x80000000u;
          unsigned int kc = (u & 0xFFFFE000u) | (unsigned int)(8191 - colv[ni]);
          kc = dead ? 0u : kc;
          kk = kk > kc ? kk : kc;
        }
        key[mi][reg] = kk;
      }
    }
  }

  // One butterfly + one atomic per owned row.
#pragma unroll
  for (int mi = 0; mi < 2; ++mi) {
#pragma unroll
    for (int reg = 0; reg < 16; ++reg) {
      unsigned int kk = key[mi][reg];
#pragma unroll
      for (int m = 1; m <= 16; m <<= 1) {
        unsigned int o = __shfl_xor(kk, m, 64);
        kk = kk > o ? kk : o;
      }
      if (r31 == 0) {
        const int row_l = 64 * wr + 32 * mi + (reg & 3) + 8 * (reg >> 2) + 4 * kh;
        atomicMax(&keys[rowBase + row_l], kk);
      }
    }
  }
}

// Exact fp32 recompute of neg_sim for the mined index + loss reduction.
// 1024 blocks -> ample wave parallelism for the latency-bound gather.
__global__ void final_kernel(const float* __restrict__ x, const float* __restrict__ y,
                             const float* __restrict__ pos,
                             const unsigned int* __restrict__ keys,
                             float* __restrict__ out) {
  const int t = threadIdx.x;
  const int lane = t & 63, wave = t >> 6;
  float accl = 0.f;
#pragma unroll
  for (int i = 0; i < 2; ++i) {
    const int row = blockIdx.x * 8 + i * 4 + wave;
    const unsigned int k = keys[row];
    const int j = (k == 0u) ? 0 : (8191 - (int)(k & 8191u));  // all-masked -> argmax 0
    const float4* xr = (const float4*)(x + (size_t)row * DDIM);
    const float4* yr = (const float4*)(y + (size_t)j * DDIM);
    float s = 0.f;
#pragma unroll
    for (int u = 0; u < 4; ++u) {
      const float4 a = xr[lane + 64 * u];
      const float4 b = yr[lane + 64 * u];
      s += a.x * b.x + a.y * b.y + a.z * b.z + a.w * b.w;
    }
    for (int m = 32; m; m >>= 1) s += __shfl_down(s, m, 64);
    if (lane == 0) {
      const float l = MARGIN_F - pos[row] + s;
      accl += l > 0.f ? l : 0.f;
    }
  }
  __shared__ float ps[4];
  if (lane == 0) ps[wave] = accl;
  __syncthreads();
  if (t == 0) atomicAdd(out, (ps[0] + ps[1] + ps[2] + ps[3]) * (1.0f / (float)NROWS));
}

extern "C" void kernel_launch(void* const* d_in, const int* in_sizes, int n_in,
                              void* d_out, int out_size, void* d_ws, size_t ws_size,
                              hipStream_t stream) {
  const float* x = (const float*)d_in[0];
  const float* y = (const float*)d_in[1];
  float* out = (float*)d_out;

  // ws layout: keys 32 KB | pos 32 KB | xq 8 MB | yq 8 MB
  unsigned int* keys = (unsigned int*)d_ws;
  float* pos = (float*)((char*)d_ws + (size_t)NROWS * 4);
  unsigned char* xq = (unsigned char*)d_ws + (size_t)NROWS * 8;
  unsigned char* yq = xq + (size_t)NROWS * DDIM;

  prep_kernel<<<NROWS / 4, 256, 0, stream>>>(x, y, (unsigned int*)xq, (unsigned int*)yq,
                                             pos, keys, out);
  dim3 grid(NROWS / BM, NSTRIPES);
  mine_kernel<<<grid, 256, 0, stream>>>(xq, yq, pos, keys);
  final_kernel<<<NROWS / 8, 256, 0, stream>>>(x, y, pos, keys, out);
}

// Round 8
// 214.418 us; speedup vs baseline: 3.0658x; 1.1275x over previous
//
#include <hip/hip_runtime.h>

#define NROWS 8192
#define DDIM  1024           // elements per row (fp8: also bytes per row)
#define BM 128
#define BN 256
#define BKB 128              // K-bytes per tile iteration
#define NSTRIPES 8
#define CT_PER_STRIPE 4      // 8192 / (256*8)
#define MARGIN_F 0.05f
#define FP8_SCALE 8.0f       // power of 2; sims are scaled by 64 in mining space

typedef __attribute__((ext_vector_type(8)))  int   int8v;
typedef __attribute__((ext_vector_type(4)))  int   int4v;
typedef __attribute__((ext_vector_type(16))) float floatx16;

__device__ __forceinline__ void g2lds16(const void* g, void* l) {
  __builtin_amdgcn_global_load_lds(
      (const __attribute__((address_space(1))) void*)g,
      (__attribute__((address_space(3))) void*)l, 16, 0, 0);
}

// prep: 2048 blocks x 256 threads; wave w handles row 4*blockIdx + w.
// Exact fp32 pos_sim, fp32 -> fp8(e4m3, x8) quantize, zero keys + out.
__global__ void prep_kernel(const float* __restrict__ x, const float* __restrict__ y,
                            unsigned int* __restrict__ xq, unsigned int* __restrict__ yq,
                            float* __restrict__ pos, unsigned int* __restrict__ keys,
                            float* __restrict__ out) {
  const int t = threadIdx.x;
  const int lane = t & 63, wave = t >> 6;
  const int row = blockIdx.x * 4 + wave;
  const float4* xr = (const float4*)(x + (size_t)row * DDIM);
  const float4* yr = (const float4*)(y + (size_t)row * DDIM);
  unsigned int* xqr = xq + (size_t)row * 256;
  unsigned int* yqr = yq + (size_t)row * 256;
  float s = 0.f;
#pragma unroll
  for (int u = 0; u < 4; ++u) {
    const float4 a = xr[u * 64 + lane];
    const float4 b = yr[u * 64 + lane];
    s += a.x * b.x + a.y * b.y + a.z * b.z + a.w * b.w;
    int pa = __builtin_amdgcn_cvt_pk_fp8_f32(a.x * FP8_SCALE, a.y * FP8_SCALE, 0, false);
    pa     = __builtin_amdgcn_cvt_pk_fp8_f32(a.z * FP8_SCALE, a.w * FP8_SCALE, pa, true);
    int pb = __builtin_amdgcn_cvt_pk_fp8_f32(b.x * FP8_SCALE, b.y * FP8_SCALE, 0, false);
    pb     = __builtin_amdgcn_cvt_pk_fp8_f32(b.z * FP8_SCALE, b.w * FP8_SCALE, pb, true);
    xqr[u * 64 + lane] = (unsigned int)pa;
    yqr[u * 64 + lane] = (unsigned int)pb;
  }
  for (int m = 32; m; m >>= 1) s += __shfl_down(s, m, 64);
  if (lane == 0) { pos[row] = s; keys[row] = 0u; }
  if (blockIdx.x == 0 && t == 0) out[0] = 0.f;
}

// MX-fp8 32x32x64 MFMA GEMM + mask + row-argmax. 128x256 tile, 2x2 waves,
// wave = 64 rows x 128 cols (2 A-frags x 4 B-frags, 8 MFMA / 12 b128 reads).
// R16 = verified-best restore (Round-0 source, 209.7us total, mine 123us).
// Session ledger of structural experiments, all measured NEGATIVE:
//  R9  dbuf+prefetch-after-barrier: null (drain was pre-satisfied; no gain)
//  R10/R12/R14 smaller tiles for occupancy: HBM-thrash (FETCH 248-899MB)
//  R11 8-phase 256^2: acc spill (WRITE 1.07GB) + HBM-bound
//  R13 counted-vmcnt depth-2: batched-frag liveness -> spill (WRITE 227MB)
//  R15 A direct-from-global: 1KB-stride gather cost > LDS-port saving (-14us)
// Conclusions baked in: staging via coalesced global_load_lds + XOR-swizzled
// LDS is the cheapest transport for BOTH operands; the 4cyc/b128 conflict tax
// is structural (exactly 4.0 x b128-count in every round); per-ni
// immediate-consume fragment reads are the no-spill envelope.
__global__ __launch_bounds__(256, 2) void mine_kernel(
    const unsigned char* __restrict__ xq, const unsigned char* __restrict__ yq,
    const float* __restrict__ pos, unsigned int* __restrict__ keys) {
  __shared__ unsigned char As[BM * BKB];  // 16 KB, XOR-swizzled
  __shared__ unsigned char Bs[BN * BKB];  // 32 KB, XOR-swizzled
  __shared__ float pos_s[BM];

  const int t = threadIdx.x;
  const int rowBase = blockIdx.x * BM;
  const int stripe  = blockIdx.y;
  if (t < BM) pos_s[t] = pos[rowBase + t] * (FP8_SCALE * FP8_SCALE);

  const int lane = t & 63;
  const int wave = t >> 6;
  const int wr = wave >> 1, wc = wave & 1;
  const int r31 = lane & 31, kh = lane >> 5;
  // Swizzle: chunk c (16B) of LDS row r lives at position c^(r&7); 32|rowstep
  // so (row&7)==(r31&7) for every tile this lane touches. ks toggles byte-
  // offset bit6 (^64); the pair's second chunk toggles bit4 (^16).
  const int fragOff = ((2 * kh) ^ (r31 & 7)) << 4;
  const int offA0 = (64 * wr + r31) * BKB + fragOff;       // mi adds 32*BKB
  const int offB0 = (128 * wc + r31) * BKB + fragOff;      // ni adds 32*BKB

  unsigned int key[2][16];
#pragma unroll
  for (int mi = 0; mi < 2; ++mi)
#pragma unroll
    for (int reg = 0; reg < 16; ++reg) key[mi][reg] = 0u;

  for (int ct = 0; ct < CT_PER_STRIPE; ++ct) {
    const int colBase = stripe * (BN * CT_PER_STRIPE) + ct * BN;

    floatx16 acc[2][4];
#pragma unroll
    for (int mi = 0; mi < 2; ++mi)
#pragma unroll
      for (int ni = 0; ni < 4; ++ni)
#pragma unroll
        for (int r = 0; r < 16; ++r) acc[mi][ni][r] = 0.f;

    for (int k0 = 0; k0 < DDIM; k0 += BKB) {
      __syncthreads();  // previous iteration's ds_reads done before overwrite
      // Stage A (16 KB, 4 issues/thread) and B (32 KB, 8 issues/thread) via
      // global_load_lds width=16. 8 consecutive lanes fill one row's 128-B
      // segment -> coalesced; swizzle carried by the global source address.
#pragma unroll
      for (int i = 0; i < 4; ++i) {
        const int c  = i * 256 + t;
        const int r  = c >> 3;               // 0..127
        const int sw = (c & 7) ^ (r & 7);
        g2lds16(xq + (size_t)(rowBase + r) * DDIM + k0 + sw * 16,
                &As[(size_t)(i * 256 + wave * 64) * 16]);
      }
#pragma unroll
      for (int i = 0; i < 8; ++i) {
        const int c  = i * 256 + t;
        const int r  = c >> 3;               // 0..255
        const int sw = (c & 7) ^ (r & 7);
        g2lds16(yq + (size_t)(colBase + r) * DDIM + k0 + sw * 16,
                &Bs[(size_t)(i * 256 + wave * 64) * 16]);
      }
      __syncthreads();

#pragma unroll
      for (int ks = 0; ks < 2; ++ks) {
        const int kx = ks << 6;  // ^64 selects the second K-64 of the tile
        int8v af[2];
#pragma unroll
        for (int mi = 0; mi < 2; ++mi) {
          const int oA = (offA0 + mi * 32 * BKB) ^ kx;
          int4v lo = *(const int4v*)&As[oA];
          int4v hi = *(const int4v*)&As[oA ^ 16];
          af[mi] = __builtin_shufflevector(lo, hi, 0, 1, 2, 3, 4, 5, 6, 7);
        }
#pragma unroll
        for (int ni = 0; ni < 4; ++ni) {
          const int oB = (offB0 + ni * 32 * BKB) ^ kx;
          int4v blo = *(const int4v*)&Bs[oB];
          int4v bhi = *(const int4v*)&Bs[oB ^ 16];
          int8v bf = __builtin_shufflevector(blo, bhi, 0, 1, 2, 3, 4, 5, 6, 7);
          acc[0][ni] = __builtin_amdgcn_mfma_scale_f32_32x32x64_f8f6f4(
              af[0], bf, acc[0][ni], 0, 0, 0, 0x7F7F7F7F, 0, 0x7F7F7F7F);
          acc[1][ni] = __builtin_amdgcn_mfma_scale_f32_32x32x64_f8f6f4(
              af[1], bf, acc[1][ni], 0, 0, 0, 0x7F7F7F7F, 0, 0x7F7F7F7F);
        }
      }
    }

    // Per-ct key update (pure VALU; no shuffles, no atomics).
    // 32x32 C/D layout (HW-verified): col = lane&31,
    // row = (reg&3) + 8*(reg>>2) + 4*(lane>>5).
    int colv[4];
#pragma unroll
    for (int ni = 0; ni < 4; ++ni) colv[ni] = colBase + 128 * wc + 32 * ni + r31;
#pragma unroll
    for (int mi = 0; mi < 2; ++mi) {
#pragma unroll
      for (int reg = 0; reg < 16; ++reg) {
        const int row_l = 64 * wr + 32 * mi + (reg & 3) + 8 * (reg >> 2) + 4 * kh;
        const int row_g = rowBase + row_l;
        const float p = pos_s[row_l];
        unsigned int kk = key[mi][reg];
#pragma unroll
        for (int ni = 0; ni < 4; ++ni) {
          const float v = acc[mi][ni][reg];
          const bool dead = (colv[ni] == row_g) || (v > p);
          unsigned int u = __float_as_uint(v);
          u ^= (unsigned int)(((int)u) >> 31) | 0x80000000u;
          unsigned int kc = (u & 0xFFFFE000u) | (unsigned int)(8191 - colv[ni]);
          kc = dead ? 0u : kc;
          kk = kk > kc ? kk : kc;
        }
        key[mi][reg] = kk;
      }
    }
  }

  // One butterfly + one atomic per owned row.
#pragma unroll
  for (int mi = 0; mi < 2; ++mi) {
#pragma unroll
    for (int reg = 0; reg < 16; ++reg) {
      unsigned int kk = key[mi][reg];
#pragma unroll
      for (int m = 1; m <= 16; m <<= 1) {
        unsigned int o = __shfl_xor(kk, m, 64);
        kk = kk > o ? kk : o;
      }
      if (r31 == 0) {
        const int row_l = 64 * wr + 32 * mi + (reg & 3) + 8 * (reg >> 2) + 4 * kh;
        atomicMax(&keys[rowBase + row_l], kk);
      }
    }
  }
}

// Exact fp32 recompute of neg_sim for the mined index + loss reduction.
__global__ void final_kernel(const float* __restrict__ x, const float* __restrict__ y,
                             const float* __restrict__ pos,
                             const unsigned int* __restrict__ keys,
                             float* __restrict__ out) {
  const int t = threadIdx.x;
  const int lane = t & 63, wave = t >> 6;
  float accl = 0.f;
#pragma unroll
  for (int i = 0; i < 8; ++i) {
    const int row = blockIdx.x * 32 + i * 4 + wave;
    const unsigned int k = keys[row];
    const int j = (k == 0u) ? 0 : (8191 - (int)(k & 8191u));  // all-masked -> argmax 0
    const float4* xr = (const float4*)(x + (size_t)row * DDIM);
    const float4* yr = (const float4*)(y + (size_t)j * DDIM);
    float s = 0.f;
#pragma unroll
    for (int u = 0; u < 4; ++u) {
      const float4 a = xr[lane + 64 * u];
      const float4 b = yr[lane + 64 * u];
      s += a.x * b.x + a.y * b.y + a.z * b.z + a.w * b.w;
    }
    for (int m = 32; m; m >>= 1) s += __shfl_down(s, m, 64);
    if (lane == 0) {
      const float l = MARGIN_F - pos[row] + s;
      accl += l > 0.f ? l : 0.f;
    }
  }
  __shared__ float ps[4];
  if (lane == 0) ps[wave] = accl;
  __syncthreads();
  if (t == 0) atomicAdd(out, (ps[0] + ps[1] + ps[2] + ps[3]) * (1.0f / (float)NROWS));
}

extern "C" void kernel_launch(void* const* d_in, const int* in_sizes, int n_in,
                              void* d_out, int out_size, void* d_ws, size_t ws_size,
                              hipStream_t stream) {
  const float* x = (const float*)d_in[0];
  const float* y = (const float*)d_in[1];
  float* out = (float*)d_out;

  // ws layout: keys 32 KB | pos 32 KB | xq 8 MB | yq 8 MB
  unsigned int* keys = (unsigned int*)d_ws;
  float* pos = (float*)((char*)d_ws + (size_t)NROWS * 4);
  unsigned char* xq = (unsigned char*)d_ws + (size_t)NROWS * 8;
  unsigned char* yq = xq + (size_t)NROWS * DDIM;

  prep_kernel<<<NROWS / 4, 256, 0, stream>>>(x, y, (unsigned int*)xq, (unsigned int*)yq,
                                             pos, keys, out);
  dim3 grid(NROWS / BM, NSTRIPES);
  mine_kernel<<<grid, 256, 0, stream>>>(xq, yq, pos, keys);
  final_kernel<<<NROWS / 32, 256, 0, stream>>>(x, y, pos, keys, out);
}